// Round 1
// baseline (724.527 us; speedup 1.0000x reference)
//
#include <hip/hip_runtime.h>
#include <hip/hip_bf16.h>
#include <cstdint>
#include <cstddef>

#define B_ 4
#define T_ 2048
#define C_ 1024
#define H_ 16
#define D_ 64
#define M_ (B_*T_)   // 8192 rows

using bf16_t = __hip_bfloat16;
typedef __bf16 v8bf __attribute__((ext_vector_type(8)));
typedef float  v4f  __attribute__((ext_vector_type(4)));

static __device__ __forceinline__ bf16_t f2bf(float v){ return __float2bfloat16(v); }

// ---------------- transpose + cast fp32[K][N] -> bf16[N][K] ----------------
__global__ void k_transpose_cast(const float* __restrict__ in, bf16_t* __restrict__ out,
                                 int K, int N){
  __shared__ float tile[32][33];
  int k0 = blockIdx.y*32, n0 = blockIdx.x*32;
  int tx = threadIdx.x, ty = threadIdx.y; // 32 x 8
  #pragma unroll
  for(int j=0;j<32;j+=8) tile[ty+j][tx] = in[(size_t)(k0+ty+j)*N + n0+tx];
  __syncthreads();
  #pragma unroll
  for(int j=0;j<32;j+=8) out[(size_t)(n0+ty+j)*K + k0+tx] = f2bf(tile[tx][ty+j]);
}

// ---------------- LayerNorm fp32 row -> bf16 row ----------------
__global__ __launch_bounds__(256) void k_layernorm(const float* __restrict__ x,
                                                   const float* __restrict__ gamma,
                                                   const float* __restrict__ beta,
                                                   bf16_t* __restrict__ out){
  int row = blockIdx.x;
  int tid = threadIdx.x;
  const float4 v = reinterpret_cast<const float4*>(x + (size_t)row*C_)[tid];
  float s  = v.x+v.y+v.z+v.w;
  float ss = v.x*v.x+v.y*v.y+v.z*v.z+v.w*v.w;
  #pragma unroll
  for(int m=1;m<64;m<<=1){ s += __shfl_xor(s,m); ss += __shfl_xor(ss,m); }
  __shared__ float sbuf[4], ssbuf[4];
  int wid = tid>>6, lane = tid&63;
  if(lane==0){ sbuf[wid]=s; ssbuf[wid]=ss; }
  __syncthreads();
  s  = sbuf[0]+sbuf[1]+sbuf[2]+sbuf[3];
  ss = ssbuf[0]+ssbuf[1]+ssbuf[2]+ssbuf[3];
  float mean = s * (1.0f/C_);
  float var  = ss * (1.0f/C_) - mean*mean;
  float rstd = rsqrtf(var + 1e-3f);
  const float4 g = reinterpret_cast<const float4*>(gamma)[tid];
  const float4 b = reinterpret_cast<const float4*>(beta)[tid];
  union { ushort4 u; bf16_t h[4]; } pk;
  pk.h[0] = f2bf(g.x*(v.x-mean)*rstd + b.x);
  pk.h[1] = f2bf(g.y*(v.y-mean)*rstd + b.y);
  pk.h[2] = f2bf(g.z*(v.z-mean)*rstd + b.z);
  pk.h[3] = f2bf(g.w*(v.w-mean)*rstd + b.w);
  *reinterpret_cast<ushort4*>(out + (size_t)row*C_ + tid*4) = pk.u;
}

// ---------------- GEMM: A[M][K]bf16 @ Bt[N][K]bf16 -> epilogue ----------------
// MODE 0: QKV split -> q[B,H,T,D], k[B,H,T,D], vt[B,H,D,T] (bf16)
// MODE 1: + bias + resid -> fp32 out
// MODE 2: + bias -> exact GELU -> bf16 out
// MODE 3: + bias + resid -> fp32 out (resid may alias out)
template<int MODE>
__global__ __launch_bounds__(256)
void k_gemm(const bf16_t* __restrict__ A, const bf16_t* __restrict__ Bt,
            const float* __restrict__ bias, const float* resid,
            void* out0, void* out1, void* out2,
            int N, int K)
{
  __shared__ __align__(16) bf16_t As[128][40];
  __shared__ __align__(16) bf16_t Bs[128][40];
  const int tid = threadIdx.x;
  const int lane = tid & 63, wid = tid >> 6;
  const int wr = wid >> 1, wc = wid & 1;
  const int row0 = blockIdx.y * 128, col0 = blockIdx.x * 128;

  v4f acc[4][4] = {};

  const int srow = tid >> 2;        // 0..63
  const int scol = (tid & 3) * 8;   // 0,8,16,24
  const bf16_t* Aptr = A  + (size_t)(row0 + srow)*K + scol;
  const bf16_t* Bptr = Bt + (size_t)(col0 + srow)*K + scol;

  for(int k0 = 0; k0 < K; k0 += 32){
    *reinterpret_cast<v8bf*>(&As[srow   ][scol]) = *reinterpret_cast<const v8bf*>(Aptr + k0);
    *reinterpret_cast<v8bf*>(&As[srow+64][scol]) = *reinterpret_cast<const v8bf*>(Aptr + (size_t)64*K + k0);
    *reinterpret_cast<v8bf*>(&Bs[srow   ][scol]) = *reinterpret_cast<const v8bf*>(Bptr + k0);
    *reinterpret_cast<v8bf*>(&Bs[srow+64][scol]) = *reinterpret_cast<const v8bf*>(Bptr + (size_t)64*K + k0);
    __syncthreads();
    v8bf af[4], bfr[4];
    #pragma unroll
    for(int m=0;m<4;m++) af[m]  = *reinterpret_cast<const v8bf*>(&As[wr*64 + m*16 + (lane&15)][(lane>>4)*8]);
    #pragma unroll
    for(int n=0;n<4;n++) bfr[n] = *reinterpret_cast<const v8bf*>(&Bs[wc*64 + n*16 + (lane&15)][(lane>>4)*8]);
    #pragma unroll
    for(int m=0;m<4;m++)
      #pragma unroll
      for(int n=0;n<4;n++)
        acc[m][n] = __builtin_amdgcn_mfma_f32_16x16x32_bf16(af[m], bfr[n], acc[m][n], 0,0,0);
    __syncthreads();
  }

  // epilogue: D[row=(lane>>4)*4+i][col=lane&15] per 16x16 frag
  #pragma unroll
  for(int m=0;m<4;m++){
    const int rbase = row0 + wr*64 + m*16 + (lane>>4)*4;
    #pragma unroll
    for(int n=0;n<4;n++){
      const int c = col0 + wc*64 + n*16 + (lane&15);
      #pragma unroll
      for(int i=0;i<4;i++){
        const int rr = rbase + i;
        float v = acc[m][n][i];
        if constexpr(MODE==0){
          const int sec = c >> 10, cc = c & 1023;
          const int h = cc >> 6, d = cc & 63;
          const int b = rr >> 11, t = rr & 2047;
          if(sec==0)      ((bf16_t*)out0)[((size_t)(b*H_ + h)*T_ + t)*D_ + d] = f2bf(v);
          else if(sec==1) ((bf16_t*)out1)[((size_t)(b*H_ + h)*T_ + t)*D_ + d] = f2bf(v);
          else            ((bf16_t*)out2)[((size_t)(b*H_ + h)*D_ + d)*T_ + t] = f2bf(v);
        } else if constexpr(MODE==1){
          ((float*)out0)[(size_t)rr*N + c] = v + bias[c] + resid[(size_t)rr*N + c];
        } else if constexpr(MODE==2){
          float o = v + bias[c];
          o = 0.5f*o*(1.0f + erff(o*0.70710678118f));
          ((bf16_t*)out0)[(size_t)rr*N + c] = f2bf(o);
        } else {
          ((float*)out0)[(size_t)rr*N + c] = v + bias[c] + resid[(size_t)rr*N + c];
        }
      }
    }
  }
}

// ---------------- causal flash attention ----------------
// Q,K: [B,H,T,D] bf16 ; Vt: [B,H,D,T] bf16 ; O: [B,T,C] bf16
__global__ __launch_bounds__(256)
void k_attn(const bf16_t* __restrict__ Q, const bf16_t* __restrict__ Kg,
            const bf16_t* __restrict__ Vt, bf16_t* __restrict__ O)
{
  __shared__ __align__(16) bf16_t Ks[32][72];
  __shared__ __align__(16) bf16_t Vts[64][40];
  __shared__ __align__(16) bf16_t Ps[4][32][40];
  const int bh = blockIdx.y;           // b*H + h
  const int qt = blockIdx.x;           // q tile of 128
  const int tid = threadIdx.x, lane = tid & 63, w = tid >> 6;
  const int qbase = qt*128 + w*32;

  // Q fragments (A operand): rows m*16+(lane&15), k = ks*32 + (lane>>4)*8
  v8bf qa[2][2];
  const bf16_t* Qb = Q + ((size_t)bh*T_ + qbase)*D_;
  #pragma unroll
  for(int m=0;m<2;m++)
    #pragma unroll
    for(int ks=0;ks<2;ks++)
      qa[m][ks] = *reinterpret_cast<const v8bf*>(Qb + (size_t)(m*16 + (lane&15))*D_ + ks*32 + (lane>>4)*8);

  v4f ob[2][4] = {};
  float mrun[2][4], lrun[2][4];
  #pragma unroll
  for(int m=0;m<2;m++)
    #pragma unroll
    for(int i=0;i<4;i++){ mrun[m][i] = -3.0e38f; lrun[m][i] = 0.0f; }

  const int nt = qt*4 + 4;
  for(int t=0;t<nt;t++){
    const int kv0 = t*32;
    { // stage K tile [32][64] and Vt tile [64][32]
      int r = tid>>3, c = (tid&7)*8;
      *reinterpret_cast<v8bf*>(&Ks[r][c]) =
        *reinterpret_cast<const v8bf*>(Kg + ((size_t)bh*T_ + kv0 + r)*D_ + c);
      int r2 = tid>>2, c2 = (tid&3)*8;
      *reinterpret_cast<v8bf*>(&Vts[r2][c2]) =
        *reinterpret_cast<const v8bf*>(Vt + ((size_t)bh*D_ + r2)*T_ + kv0 + c2);
    }
    __syncthreads();

    // S = Q K^T  (32x32 per wave)
    v4f s[2][2] = {};
    #pragma unroll
    for(int n=0;n<2;n++)
      #pragma unroll
      for(int ks=0;ks<2;ks++){
        v8bf kb = *reinterpret_cast<const v8bf*>(&Ks[n*16 + (lane&15)][ks*32 + (lane>>4)*8]);
        #pragma unroll
        for(int m=0;m<2;m++)
          s[m][n] = __builtin_amdgcn_mfma_f32_16x16x32_bf16(qa[m][ks], kb, s[m][n], 0,0,0);
      }

    // scale + causal mask + online softmax
    #pragma unroll
    for(int m=0;m<2;m++){
      #pragma unroll
      for(int i=0;i<4;i++){
        const int rg = qbase + m*16 + (lane>>4)*4 + i;
        float s0 = s[m][0][i]*0.125f, s1 = s[m][1][i]*0.125f;
        const int c0 = kv0 + (lane&15), c1 = c0 + 16;
        if(c0 > rg) s0 = -1e9f;
        if(c1 > rg) s1 = -1e9f;
        float rmax = fmaxf(s0, s1);
        rmax = fmaxf(rmax, __shfl_xor(rmax,1));
        rmax = fmaxf(rmax, __shfl_xor(rmax,2));
        rmax = fmaxf(rmax, __shfl_xor(rmax,4));
        rmax = fmaxf(rmax, __shfl_xor(rmax,8));
        const float mnew = fmaxf(mrun[m][i], rmax);
        const float corr = __expf(mrun[m][i] - mnew);
        mrun[m][i] = mnew;
        const float p0 = __expf(s0 - mnew), p1 = __expf(s1 - mnew);
        float rs = p0 + p1;
        rs += __shfl_xor(rs,1); rs += __shfl_xor(rs,2);
        rs += __shfl_xor(rs,4); rs += __shfl_xor(rs,8);
        lrun[m][i] = lrun[m][i]*corr + rs;
        #pragma unroll
        for(int d=0;d<4;d++) ob[m][d][i] *= corr;
        const int pr = m*16 + (lane>>4)*4 + i;
        Ps[w][pr][(lane&15)]      = f2bf(p0);
        Ps[w][pr][16 + (lane&15)] = f2bf(p1);
      }
    }

    // O += P V   (P: A operand [32q x 32kv], Vt rows are d)
    #pragma unroll
    for(int m=0;m<2;m++){
      v8bf pa = *reinterpret_cast<const v8bf*>(&Ps[w][m*16 + (lane&15)][(lane>>4)*8]);
      #pragma unroll
      for(int d=0;d<4;d++){
        v8bf vb = *reinterpret_cast<const v8bf*>(&Vts[d*16 + (lane&15)][(lane>>4)*8]);
        ob[m][d] = __builtin_amdgcn_mfma_f32_16x16x32_bf16(pa, vb, ob[m][d], 0,0,0);
      }
    }
    __syncthreads();
  }

  // normalize + store O as [B,T,C]
  const int b = bh >> 4, h = bh & 15;
  #pragma unroll
  for(int m=0;m<2;m++)
    #pragma unroll
    for(int i=0;i<4;i++){
      const float inv = 1.0f / lrun[m][i];
      const int tg = qbase + m*16 + (lane>>4)*4 + i;
      #pragma unroll
      for(int d=0;d<4;d++)
        O[((size_t)(b*T_ + tg))*C_ + h*D_ + d*16 + (lane&15)] = f2bf(ob[m][d][i]*inv);
    }
}

// ---------------- launch ----------------
extern "C" void kernel_launch(void* const* d_in, const int* in_sizes, int n_in,
                              void* d_out, int out_size, void* d_ws, size_t ws_size,
                              hipStream_t stream) {
  const float* x      = (const float*)d_in[0];
  const float* w_qkv  = (const float*)d_in[1];
  const float* w_proj = (const float*)d_in[2];
  const float* b_proj = (const float*)d_in[3];
  const float* w1     = (const float*)d_in[4];
  const float* b1     = (const float*)d_in[5];
  const float* w2     = (const float*)d_in[6];
  const float* b2     = (const float*)d_in[7];
  const float* gamma1 = (const float*)d_in[8];
  const float* beta1  = (const float*)d_in[9];
  const float* gamma2 = (const float*)d_in[10];
  const float* beta2  = (const float*)d_in[11];

  char* ws = (char*)d_ws;
  bf16_t* wqkv_t  = (bf16_t*)(ws + 0);           // 3072x1024  (6,291,456 B)
  bf16_t* wproj_t = (bf16_t*)(ws + 6291456);     // 1024x1024  (2,097,152 B)
  bf16_t* w1_t    = (bf16_t*)(ws + 8388608);     // 4096x1024  (8,388,608 B)
  bf16_t* w2_t    = (bf16_t*)(ws + 16777216);    // 1024x4096  (8,388,608 B)
  bf16_t* qb      = (bf16_t*)(ws + 25165824);    // [B,H,T,D]  16 MB
  bf16_t* kb      = (bf16_t*)(ws + 41943040);    // [B,H,T,D]  16 MB
  bf16_t* vtb     = (bf16_t*)(ws + 58720256);    // [B,H,D,T]  16 MB
  bf16_t* obuf    = (bf16_t*)(ws + 75497472);    // [B,T,C]    16 MB
  bf16_t* hb      = (bf16_t*)(ws + 92274688);    // [M,C] bf16 16 MB (h1 then h2)
  bf16_t* gb      = (bf16_t*)(ws + 25165824);    // [M,4C] bf16 64 MB (reuses q..o)
  float*  x2      = (float*)d_out;               // x after attn residual (aliases out)

  dim3 tb(32,8);
  k_transpose_cast<<<dim3(3072/32, 1024/32), tb, 0, stream>>>(w_qkv,  wqkv_t, 1024, 3072);
  k_transpose_cast<<<dim3(1024/32, 1024/32), tb, 0, stream>>>(w_proj, wproj_t,1024, 1024);
  k_transpose_cast<<<dim3(4096/32, 1024/32), tb, 0, stream>>>(w1,     w1_t,   1024, 4096);
  k_transpose_cast<<<dim3(1024/32, 4096/32), tb, 0, stream>>>(w2,     w2_t,   4096, 1024);

  k_layernorm<<<M_, 256, 0, stream>>>(x, gamma1, beta1, hb);

  k_gemm<0><<<dim3(3072/128, M_/128), 256, 0, stream>>>(hb, wqkv_t, nullptr, nullptr,
                                                        qb, kb, vtb, 3072, 1024);
  k_attn<<<dim3(T_/128, B_*H_), 256, 0, stream>>>(qb, kb, vtb, obuf);

  k_gemm<1><<<dim3(1024/128, M_/128), 256, 0, stream>>>(obuf, wproj_t, b_proj, x,
                                                        x2, nullptr, nullptr, 1024, 1024);
  k_layernorm<<<M_, 256, 0, stream>>>(x2, gamma2, beta2, hb);

  k_gemm<2><<<dim3(4096/128, M_/128), 256, 0, stream>>>(hb, w1_t, b1, nullptr,
                                                        gb, nullptr, nullptr, 4096, 1024);
  k_gemm<3><<<dim3(1024/128, M_/128), 256, 0, stream>>>(gb, w2_t, b2, x2,
                                                        d_out, nullptr, nullptr, 1024, 4096);
}

// Round 3
// 525.316 us; speedup vs baseline: 1.3792x; 1.3792x over previous
//
#include <hip/hip_runtime.h>
#include <hip/hip_bf16.h>
#include <cstdint>
#include <cstddef>

#define B_ 4
#define T_ 2048
#define C_ 1024
#define H_ 16
#define D_ 64
#define M_ (B_*T_)   // 8192 rows

using bf16_t = __hip_bfloat16;
typedef __bf16 v8bf __attribute__((ext_vector_type(8)));
typedef float  v4f  __attribute__((ext_vector_type(4)));
typedef float  f32x16 __attribute__((ext_vector_type(16)));

// 1/sqrt(D) * log2(e): folded into Q at the QKV epilogue; softmax in exp2 domain.
#define QSCALE (0.125f * 1.44269504088896340736f)

static __device__ __forceinline__ bf16_t f2bf(float v){ return __float2bfloat16(v); }

// async global->LDS, 16B per lane. LDS dest is wave-uniform base + lane*16.
static __device__ __forceinline__ void glds16(const bf16_t* g, bf16_t* l){
  __builtin_amdgcn_global_load_lds((__attribute__((address_space(1))) void*)g,
                                   (__attribute__((address_space(3))) void*)l, 16, 0, 0);
}

static __device__ __forceinline__ uint32_t cvt_pk_bf16(float lo, float hi){
  uint32_t w;
  asm("v_cvt_pk_bf16_f32 %0, %1, %2" : "=v"(w) : "v"(lo), "v"(hi));
  return w;
}

// ---------------- transpose + cast fp32[K][N] -> bf16[N][K] ----------------
__global__ void k_transpose_cast(const float* __restrict__ in, bf16_t* __restrict__ out,
                                 int K, int N){
  __shared__ float tile[32][33];
  int k0 = blockIdx.y*32, n0 = blockIdx.x*32;
  int tx = threadIdx.x, ty = threadIdx.y; // 32 x 8
  #pragma unroll
  for(int j=0;j<32;j+=8) tile[ty+j][tx] = in[(size_t)(k0+ty+j)*N + n0+tx];
  __syncthreads();
  #pragma unroll
  for(int j=0;j<32;j+=8) out[(size_t)(n0+ty+j)*K + k0+tx] = f2bf(tile[tx][ty+j]);
}

// ---------------- LayerNorm fp32 row -> bf16 row ----------------
__global__ __launch_bounds__(256) void k_layernorm(const float* __restrict__ x,
                                                   const float* __restrict__ gamma,
                                                   const float* __restrict__ beta,
                                                   bf16_t* __restrict__ out){
  int row = blockIdx.x;
  int tid = threadIdx.x;
  const float4 v = reinterpret_cast<const float4*>(x + (size_t)row*C_)[tid];
  float s  = v.x+v.y+v.z+v.w;
  float ss = v.x*v.x+v.y*v.y+v.z*v.z+v.w*v.w;
  #pragma unroll
  for(int m=1;m<64;m<<=1){ s += __shfl_xor(s,m); ss += __shfl_xor(ss,m); }
  __shared__ float sbuf[4], ssbuf[4];
  int wid = tid>>6, lane = tid&63;
  if(lane==0){ sbuf[wid]=s; ssbuf[wid]=ss; }
  __syncthreads();
  s  = sbuf[0]+sbuf[1]+sbuf[2]+sbuf[3];
  ss = ssbuf[0]+ssbuf[1]+ssbuf[2]+ssbuf[3];
  float mean = s * (1.0f/C_);
  float var  = ss * (1.0f/C_) - mean*mean;
  float rstd = rsqrtf(var + 1e-3f);
  const float4 g = reinterpret_cast<const float4*>(gamma)[tid];
  const float4 b = reinterpret_cast<const float4*>(beta)[tid];
  union { ushort4 u; bf16_t h[4]; } pk;
  pk.h[0] = f2bf(g.x*(v.x-mean)*rstd + b.x);
  pk.h[1] = f2bf(g.y*(v.y-mean)*rstd + b.y);
  pk.h[2] = f2bf(g.z*(v.z-mean)*rstd + b.z);
  pk.h[3] = f2bf(g.w*(v.w-mean)*rstd + b.w);
  *reinterpret_cast<ushort4*>(out + (size_t)row*C_ + tid*4) = pk.u;
}

// ---------------- GEMM (m97 structure): A[M][K]bf16 @ Bt[N][K]bf16 ----------------
// MODE 0: QKV split -> q*QSCALE[B,H,T,D], k[B,H,T,D], vt[B,H,D,T] (bf16)
// MODE 1: + bias + resid -> fp32 out
// MODE 2: + bias -> exact GELU -> bf16 out
// MODE 3: + bias + resid -> fp32 out (resid may alias out)
template<int MODE>
__global__ __launch_bounds__(256)
void k_gemm(const bf16_t* __restrict__ A, const bf16_t* __restrict__ Bt,
            const float* __restrict__ bias, const float* resid,
            void* out0, void* out1, void* out2,
            int N, int K)
{
  __shared__ __align__(16) bf16_t As[128][32];   // linear: required by global_load_lds
  __shared__ __align__(16) bf16_t Bs[128][32];
  const int tid = threadIdx.x;
  const int lane = tid & 63, wid = tid >> 6;
  const int wr = wid >> 1, wc = wid & 1;
  const int row0 = blockIdx.y * 128, col0 = blockIdx.x * 128;

  v4f acc[4][4] = {};

  // wave w stages rows [w*32, w*32+32): 2 loads of 16 rows (64B/row, lane covers 16B)
  const int grow = wid*32 + (lane>>2);
  const int gcol = (lane&3)*8;
  const bf16_t* Ag = A  + (size_t)(row0 + grow)*K + gcol;
  const bf16_t* Bg = Bt + (size_t)(col0 + grow)*K + gcol;
  bf16_t* Al0 = &As[wid*32   ][0];
  bf16_t* Al1 = &As[wid*32+16][0];
  bf16_t* Bl0 = &Bs[wid*32   ][0];
  bf16_t* Bl1 = &Bs[wid*32+16][0];

  for(int k0 = 0; k0 < K; k0 += 32){
    glds16(Ag + k0,                Al0);
    glds16(Ag + (size_t)16*K + k0, Al1);
    glds16(Bg + k0,                Bl0);
    glds16(Bg + (size_t)16*K + k0, Bl1);
    __syncthreads();
    v8bf af[4], bfr[4];
    #pragma unroll
    for(int m=0;m<4;m++) af[m]  = *reinterpret_cast<const v8bf*>(&As[wr*64 + m*16 + (lane&15)][(lane>>4)*8]);
    #pragma unroll
    for(int n=0;n<4;n++) bfr[n] = *reinterpret_cast<const v8bf*>(&Bs[wc*64 + n*16 + (lane&15)][(lane>>4)*8]);
    #pragma unroll
    for(int m=0;m<4;m++)
      #pragma unroll
      for(int n=0;n<4;n++)
        acc[m][n] = __builtin_amdgcn_mfma_f32_16x16x32_bf16(af[m], bfr[n], acc[m][n], 0,0,0);
    __syncthreads();
  }

  // epilogue: D[row=(lane>>4)*4+i][col=lane&15] per 16x16 frag
  #pragma unroll
  for(int m=0;m<4;m++){
    const int rbase = row0 + wr*64 + m*16 + (lane>>4)*4;
    #pragma unroll
    for(int n=0;n<4;n++){
      const int c = col0 + wc*64 + n*16 + (lane&15);
      #pragma unroll
      for(int i=0;i<4;i++){
        const int rr = rbase + i;
        float v = acc[m][n][i];
        if constexpr(MODE==0){
          const int sec = c >> 10, cc = c & 1023;
          const int h = cc >> 6, d = cc & 63;
          const int b = rr >> 11, t = rr & 2047;
          if(sec==0)      ((bf16_t*)out0)[((size_t)(b*H_ + h)*T_ + t)*D_ + d] = f2bf(v * QSCALE);
          else if(sec==1) ((bf16_t*)out1)[((size_t)(b*H_ + h)*T_ + t)*D_ + d] = f2bf(v);
          else            ((bf16_t*)out2)[((size_t)(b*H_ + h)*D_ + d)*T_ + t] = f2bf(v);
        } else if constexpr(MODE==1){
          ((float*)out0)[(size_t)rr*N + c] = v + bias[c] + resid[(size_t)rr*N + c];
        } else if constexpr(MODE==2){
          float o = v + bias[c];
          o = 0.5f*o*(1.0f + erff(o*0.70710678118f));
          ((bf16_t*)out0)[(size_t)rr*N + c] = f2bf(o);
        } else {
          ((float*)out0)[(size_t)rr*N + c] = v + bias[c] + resid[(size_t)rr*N + c];
        }
      }
    }
  }
}

// ---------------- causal flash attention, swapped-operand 32x32 ----------------
// Q(pre-scaled): [B,H,T,D] bf16 ; K: [B,H,T,D] bf16 ; Vt: [B,H,D,T] bf16 ; O: [B,T,C] bf16
// Per wave: 32 q rows. S^T = K · Q^T  (lane owns q = lane&31; 32 kv scores in-register).
// O^T = V^T · P^T keeps q lane-local for rescale/normalize.
__global__ __launch_bounds__(256)
void k_attn(const bf16_t* __restrict__ Q, const bf16_t* __restrict__ Kg,
            const bf16_t* __restrict__ Vt, bf16_t* __restrict__ O)
{
  __shared__ __align__(16) bf16_t Ks [64][72];   // [kv][d]   stride 144B
  __shared__ __align__(16) bf16_t Vts[64][72];   // [d][kv]
  __shared__ __align__(16) bf16_t Os [128][72];  // [q][d] transpose buffer
  const int bh = blockIdx.y;
  const int qt = blockIdx.x;
  const int tid = threadIdx.x, lane = tid & 63, w = tid >> 6;
  const int ql = lane & 31, hi = lane >> 5;
  const int qbase = qt*128 + w*32;
  const int q = qbase + ql;

  // Q fragments (B-operand): col=q=lane&31, k(d) = ds*16 + hi*8
  v8bf qf[4];
  {
    const bf16_t* Qb = Q + ((size_t)bh*T_ + q)*D_ + hi*8;
    #pragma unroll
    for(int ds=0; ds<4; ds++)
      qf[ds] = *reinterpret_cast<const v8bf*>(Qb + ds*16);
  }

  f32x16 accO[2] = {};          // O^T: col=q (lane-local), row d = dh*32 + (r&3)+8*(r>>2)+4*hi
  float mrun = -1e30f, lrun = 0.0f;

  const int NT = (qt + 1) * 2;  // 64-wide kv tiles
  const int srow = tid >> 2;          // 0..63
  const int scol = (tid & 3) * 16;    // 0,16,32,48
  const bf16_t* Kgp = Kg + ((size_t)bh*T_ + srow)*D_ + scol;
  const bf16_t* Vtp = Vt + ((size_t)bh*D_ + srow)*T_ + scol;

  for(int t=0; t<NT; t++){
    const int kv0 = t*64;
    // stage K[64 kv][64 d] and Vt[64 d][64 kv]
    *reinterpret_cast<v8bf*>(&Ks [srow][scol  ]) = *reinterpret_cast<const v8bf*>(Kgp + (size_t)kv0*D_);
    *reinterpret_cast<v8bf*>(&Ks [srow][scol+8]) = *reinterpret_cast<const v8bf*>(Kgp + (size_t)kv0*D_ + 8);
    *reinterpret_cast<v8bf*>(&Vts[srow][scol  ]) = *reinterpret_cast<const v8bf*>(Vtp + kv0);
    *reinterpret_cast<v8bf*>(&Vts[srow][scol+8]) = *reinterpret_cast<const v8bf*>(Vtp + kv0 + 8);
    __syncthreads();

    if(kv0 <= qbase + 31){      // wave-uniform: skip fully-masked tiles
      // S^T = K * Q^T
      f32x16 sT[2] = {};
      #pragma unroll
      for(int kvh=0; kvh<2; kvh++)
        #pragma unroll
        for(int ds=0; ds<4; ds++){
          v8bf kf = *reinterpret_cast<const v8bf*>(&Ks[kvh*32 + ql][ds*16 + hi*8]);
          sT[kvh] = __builtin_amdgcn_mfma_f32_32x32x16_bf16(kf, qf[ds], sT[kvh], 0,0,0);
        }

      if(kv0 + 63 > qbase){     // diagonal tile: causal mask (kv index = kvh*32+(r&3)+8*(r>>2)+4*hi)
        const int qrel = q - kv0 - hi*4;
        #pragma unroll
        for(int kvh=0; kvh<2; kvh++)
          #pragma unroll
          for(int r=0; r<16; r++){
            const int c = kvh*32 + (r&3) + 8*(r>>2);
            if(c > qrel) sT[kvh][r] = -1e30f;
          }
      }

      // in-lane row max over 32 scores + partner half
      float pm = sT[0][0];
      #pragma unroll
      for(int r=1; r<16; r++) pm = fmaxf(pm, sT[0][r]);
      #pragma unroll
      for(int r=0; r<16; r++) pm = fmaxf(pm, sT[1][r]);
      pm = fmaxf(pm, __shfl_xor(pm, 32));
      const float mnew = fmaxf(mrun, pm);
      const float corr = __builtin_amdgcn_exp2f(mrun - mnew);
      mrun = mnew;
      float rs = 0.0f;
      #pragma unroll
      for(int kvh=0; kvh<2; kvh++)
        #pragma unroll
        for(int r=0; r<16; r++){
          float p = __builtin_amdgcn_exp2f(sT[kvh][r] - mnew);
          sT[kvh][r] = p;
          rs += p;
        }
      rs += __shfl_xor(rs, 32);
      lrun = lrun*corr + rs;
      #pragma unroll
      for(int dh=0; dh<2; dh++)
        #pragma unroll
        for(int r=0; r<16; r++) accO[dh][r] *= corr;

      // pack P -> bf16 B-operand fragments (kv slices of 16).
      // Lane (q=ql, hi) needs P[q][kv = s4*16 + hi*8 + j], j=0..7.
      // Own C-layout holds kv_local (r&3)+8*(r>>2)+4*hi; partner (lane^32) holds the
      // complementary 4-interleave. Exchange via well-defined __shfl_xor(.,32):
      //   word0 = hi? xwc : wa;  word1 = hi? xwd : wb;
      //   word2 = hi? wc : xwa;  word3 = hi? wd : xwb;   (x* = partner's value)
      v8bf pfrag[4];
      #pragma unroll
      for(int s4=0; s4<4; s4++){
        const int kvh = s4>>1, bb = (s4&1)*8;
        uint32_t wa = cvt_pk_bf16(sT[kvh][bb+0], sT[kvh][bb+1]);
        uint32_t wb = cvt_pk_bf16(sT[kvh][bb+2], sT[kvh][bb+3]);
        uint32_t wc = cvt_pk_bf16(sT[kvh][bb+4], sT[kvh][bb+5]);
        uint32_t wd = cvt_pk_bf16(sT[kvh][bb+6], sT[kvh][bb+7]);
        uint32_t xwa = (uint32_t)__shfl_xor((int)wa, 32);
        uint32_t xwb = (uint32_t)__shfl_xor((int)wb, 32);
        uint32_t xwc = (uint32_t)__shfl_xor((int)wc, 32);
        uint32_t xwd = (uint32_t)__shfl_xor((int)wd, 32);
        union { uint32_t u[4]; v8bf v; } pk;
        pk.u[0] = hi ? xwc : wa;
        pk.u[1] = hi ? xwd : wb;
        pk.u[2] = hi ? wc  : xwa;
        pk.u[3] = hi ? wd  : xwb;
        pfrag[s4] = pk.v;
      }

      // O^T += V^T * P^T
      #pragma unroll
      for(int dh=0; dh<2; dh++)
        #pragma unroll
        for(int s4=0; s4<4; s4++){
          v8bf vf = *reinterpret_cast<const v8bf*>(&Vts[dh*32 + ql][s4*16 + hi*8]);
          accO[dh] = __builtin_amdgcn_mfma_f32_32x32x16_bf16(vf, pfrag[s4], accO[dh], 0,0,0);
        }
    }
    __syncthreads();
  }

  // normalize (lane-local) and transpose through LDS for coalesced store
  const float inv = 1.0f / lrun;
  #pragma unroll
  for(int dh=0; dh<2; dh++)
    #pragma unroll
    for(int rg=0; rg<4; rg++){
      uint32_t lo_ = cvt_pk_bf16(accO[dh][rg*4+0]*inv, accO[dh][rg*4+1]*inv);
      uint32_t hi_ = cvt_pk_bf16(accO[dh][rg*4+2]*inv, accO[dh][rg*4+3]*inv);
      uint2 w2; w2.x = lo_; w2.y = hi_;
      *reinterpret_cast<uint2*>(&Os[w*32 + ql][dh*32 + rg*8 + hi*4]) = w2;
    }
  __syncthreads();
  const int b = bh >> 4, h = bh & 15;
  const int orow = tid >> 1, ocol = (tid & 1) * 32;
  bf16_t* Og = O + ((size_t)(b*T_ + qt*128 + orow))*C_ + h*64 + ocol;
  #pragma unroll
  for(int j=0;j<4;j++)
    *reinterpret_cast<v8bf*>(Og + j*8) = *reinterpret_cast<const v8bf*>(&Os[orow][ocol + j*8]);
}

// ---------------- launch ----------------
extern "C" void kernel_launch(void* const* d_in, const int* in_sizes, int n_in,
                              void* d_out, int out_size, void* d_ws, size_t ws_size,
                              hipStream_t stream) {
  const float* x      = (const float*)d_in[0];
  const float* w_qkv  = (const float*)d_in[1];
  const float* w_proj = (const float*)d_in[2];
  const float* b_proj = (const float*)d_in[3];
  const float* w1     = (const float*)d_in[4];
  const float* b1     = (const float*)d_in[5];
  const float* w2     = (const float*)d_in[6];
  const float* b2     = (const float*)d_in[7];
  const float* gamma1 = (const float*)d_in[8];
  const float* beta1  = (const float*)d_in[9];
  const float* gamma2 = (const float*)d_in[10];
  const float* beta2  = (const float*)d_in[11];

  char* ws = (char*)d_ws;
  bf16_t* wqkv_t  = (bf16_t*)(ws + 0);           // 3072x1024
  bf16_t* wproj_t = (bf16_t*)(ws + 6291456);     // 1024x1024
  bf16_t* w1_t    = (bf16_t*)(ws + 8388608);     // 4096x1024
  bf16_t* w2_t    = (bf16_t*)(ws + 16777216);    // 1024x4096
  bf16_t* qb      = (bf16_t*)(ws + 25165824);    // [B,H,T,D]
  bf16_t* kb      = (bf16_t*)(ws + 41943040);    // [B,H,T,D]
  bf16_t* vtb     = (bf16_t*)(ws + 58720256);    // [B,H,D,T]
  bf16_t* obuf    = (bf16_t*)(ws + 75497472);    // [B,T,C]
  bf16_t* hb      = (bf16_t*)(ws + 92274688);    // [M,C] bf16
  bf16_t* gb      = (bf16_t*)(ws + 25165824);    // [M,4C] bf16 (reuses q..o)
  float*  x2      = (float*)d_out;               // x after attn residual (aliases out)

  dim3 tb(32,8);
  k_transpose_cast<<<dim3(3072/32, 1024/32), tb, 0, stream>>>(w_qkv,  wqkv_t, 1024, 3072);
  k_transpose_cast<<<dim3(1024/32, 1024/32), tb, 0, stream>>>(w_proj, wproj_t,1024, 1024);
  k_transpose_cast<<<dim3(4096/32, 1024/32), tb, 0, stream>>>(w1,     w1_t,   1024, 4096);
  k_transpose_cast<<<dim3(1024/32, 4096/32), tb, 0, stream>>>(w2,     w2_t,   4096, 1024);

  k_layernorm<<<M_, 256, 0, stream>>>(x, gamma1, beta1, hb);

  k_gemm<0><<<dim3(3072/128, M_/128), 256, 0, stream>>>(hb, wqkv_t, nullptr, nullptr,
                                                        qb, kb, vtb, 3072, 1024);
  k_attn<<<dim3(T_/128, B_*H_), 256, 0, stream>>>(qb, kb, vtb, obuf);

  k_gemm<1><<<dim3(1024/128, M_/128), 256, 0, stream>>>(obuf, wproj_t, b_proj, x,
                                                        x2, nullptr, nullptr, 1024, 1024);
  k_layernorm<<<M_, 256, 0, stream>>>(x2, gamma2, beta2, hb);

  k_gemm<2><<<dim3(4096/128, M_/128), 256, 0, stream>>>(hb, w1_t, b1, nullptr,
                                                        gb, nullptr, nullptr, 4096, 1024);
  k_gemm<3><<<dim3(1024/128, M_/128), 256, 0, stream>>>(gb, w2_t, b2, x2,
                                                        d_out, nullptr, nullptr, 1024, 4096);
}